// Round 7
// baseline (232.251 us; speedup 1.0000x reference)
//
#include <hip/hip_runtime.h>
#include <hip/hip_cooperative_groups.h>
#include <math.h>

namespace cg = cooperative_groups;

#define Bsz 64
#define Tn 200
#define NUMC 2000
#define DS 128
#define SM 50
#define NTOK (Bsz*Tn)
#define WG2 10       // m-groups in scan
#define MPG2 5       // m per group (WG2*MPG2 == SM)

typedef __attribute__((ext_vector_type(8))) short bfrag;
typedef __attribute__((ext_vector_type(4))) float f32x4;
typedef __attribute__((ext_vector_type(4))) unsigned int u32x4;

__device__ __forceinline__ unsigned short f2bf(float x) {
    unsigned int u = __builtin_bit_cast(unsigned int, x);
    u = u + 0x7fffu + ((u >> 16) & 1u);   // RNE
    return (unsigned short)(u >> 16);
}
__device__ __forceinline__ unsigned int pack2(float a, float b) {
    return (unsigned int)f2bf(a) | ((unsigned int)f2bf(b) << 16);
}
__device__ __forceinline__ float bf2f(unsigned int u) {
    return __builtin_bit_cast(float, u << 16);
}
__device__ __forceinline__ bfrag mk_frag(f32x4 x, f32x4 y) {
    u32x4 t;
    t[0] = pack2(x[0], x[1]); t[1] = pack2(x[2], x[3]);
    t[2] = pack2(y[0], y[1]); t[3] = pack2(y[2], y[3]);
    return __builtin_bit_cast(bfrag, t);
}

// fast transcendentals: v_exp_f32 / v_rcp_f32 (~1e-6 rel err, invisible at bf16 grade)
__device__ __forceinline__ float fast_exp(float x)  { return __builtin_amdgcn_exp2f(x * 1.44269504f); }
__device__ __forceinline__ float fast_rcp(float x)  { return __builtin_amdgcn_rcpf(x); }
__device__ __forceinline__ float fast_sigmoid(float x) { return fast_rcp(1.f + fast_exp(-x)); }
__device__ __forceinline__ float fast_tanh(float x) { return 1.f - 2.f * fast_rcp(fast_exp(2.f * x) + 1.f); }

__device__ __forceinline__ void load_group(const bfrag* __restrict__ B, int nt0, int L, bfrag bf[4][4]) {
    #pragma unroll
    for (int t = 0; t < 4; t++)
        #pragma unroll
        for (int ki = 0; ki < 4; ki++)
            bf[t][ki] = B[(size_t)((nt0 + t) * 4 + ki) * 64 + L];
}
__device__ __forceinline__ void mfma_group(const bfrag A[4], const bfrag bf[4][4], f32x4 acc[4]) {
    #pragma unroll
    for (int ki = 0; ki < 4; ki++)
        #pragma unroll
        for (int t = 0; t < 4; t++)
            acc[t] = __builtin_amdgcn_mfma_f32_16x16x32_bf16(A[ki], bf[t][ki], acc[t], 0, 0, 0);
}

// ===================== single fused cooperative kernel =====================
// 256 blocks x 512 threads (8 waves/block, 1 block/CU, LDS=0).
// Phase 0: weight cast -> frag buffers.  Phase A: EA/KM GEMMs (in-wave softmax).
// Phase B: sequential scan (1-wave tasks, bf16 partials).  Phase C: f-GEMM + pred.
__global__ __launch_bounds__(512, 2) void fused(
    const int* __restrict__ skill, const int* __restrict__ answer,
    const float* __restrict__ k_emb, const float* __restrict__ v_emb,
    const float* __restrict__ Mk, const float* __restrict__ Mv0,
    const float* __restrict__ fW, const float* __restrict__ fB,
    const float* __restrict__ pW, const float* __restrict__ pB,
    const float* __restrict__ eW, const float* __restrict__ eB,
    const float* __restrict__ aW, const float* __restrict__ aB,
    float* __restrict__ out,
    float* __restrict__ w_buf, float* __restrict__ e_buf,
    float* __restrict__ a_buf, float* __restrict__ kp_buf,
    unsigned short* __restrict__ part16,
    unsigned int* __restrict__ BeaU, unsigned int* __restrict__ BkmU,
    unsigned int* __restrict__ Bf0U)
{
    cg::grid_group grid = cg::this_grid();
    const int tid = threadIdx.x;
    const int wv  = tid >> 6;                  // wave in block, 0..7
    const int L   = tid & 63, L15 = L & 15, quad = (L >> 4) & 3;

    // ---------- Phase 0: cast weights into MFMA b-frag block layout ----------
    // lane L holds W[n = nt*16 + (L&15)][k = ki*32 + (L>>4)*8 + j], j=0..7.
    {
        const int g = blockIdx.x * 512 + tid;
        if (g < 9216) {
            int gm, mat;
            unsigned int* dst;
            if (g < 4096)      { mat = 0; gm = g;        dst = BeaU; }
            else if (g < 7168) { mat = 1; gm = g - 4096; dst = BkmU; }
            else               { mat = 2; gm = g - 7168; dst = Bf0U; }
            const int nt = gm >> 8, r = gm & 255, ki = r >> 6, Lc = r & 63;
            const int n = nt * 16 + (Lc & 15);
            const int k = ki * 32 + (Lc >> 4) * 8;
            const float* src = nullptr;
            if (mat == 0) {
                src = (n < 128) ? (eW + (size_t)n * DS + k) : (aW + (size_t)(n - 128) * DS + k);
            } else if (mat == 1) {
                if (n < 128)           src = fW + (size_t)n * (2 * DS) + DS + k;
                else if (n < 128 + SM) src = Mk + (size_t)(n - 128) * DS + k;
            } else {
                src = fW + (size_t)n * (2 * DS) + k;
            }
            float v[8];
            #pragma unroll
            for (int j = 0; j < 8; j++) v[j] = src ? src[j] : 0.f;
            u32x4 o;
            o[0] = pack2(v[0], v[1]); o[1] = pack2(v[2], v[3]);
            o[2] = pack2(v[4], v[5]); o[3] = pack2(v[6], v[7]);
            ((u32x4*)dst)[gm] = o;
        }
    }
    grid.sync();

    // ---------- Phase A: 1600 wave-tasks; tA<800 EA, else KM ----------
    {
        const int tA = wv * 256 + blockIdx.x;   // spread tasks across CUs
        if (tA < 800) {
            const int tok0 = tA * 16;
            const int tokA = tok0 + L15;
            const int tokD0 = tok0 + quad * 4;

            const bfrag* Bea = (const bfrag*)BeaU;
            bfrag bfA[4][4], bfB[4][4];
            load_group(Bea, 0, L, bfA);
            load_group(Bea, 4, L, bfB);

            const int s  = skill[tokA];
            const int an = answer[tokA];
            const int ax = (an == 2) ? 1 : an;
            const float* vp = v_emb + ((size_t)(s + NUMC * ax)) * DS + quad * 8;
            bfrag Vf[4];
            #pragma unroll
            for (int ki = 0; ki < 4; ki++) {
                const f32x4* a = (const f32x4*)(vp + ki * 32);
                Vf[ki] = mk_frag(a[0], a[1]);
            }

            f32x4 acc[4];
            #pragma unroll
            for (int t = 0; t < 4; t++) acc[t] = (f32x4){0.f,0.f,0.f,0.f};
            mfma_group(Vf, bfA, acc);
            load_group(Bea, 8, L, bfA);
            #pragma unroll
            for (int t = 0; t < 4; t++) {
                const int n = t * 16 + L15;
                const float bias = eB[n];
                #pragma unroll
                for (int reg = 0; reg < 4; reg++)
                    e_buf[(size_t)(tokD0 + reg) * DS + n] = fast_sigmoid(acc[t][reg] + bias);
            }

            #pragma unroll
            for (int t = 0; t < 4; t++) acc[t] = (f32x4){0.f,0.f,0.f,0.f};
            mfma_group(Vf, bfB, acc);
            load_group(Bea, 12, L, bfB);
            #pragma unroll
            for (int t = 0; t < 4; t++) {
                const int n = (4 + t) * 16 + L15;
                const float bias = eB[n];
                #pragma unroll
                for (int reg = 0; reg < 4; reg++)
                    e_buf[(size_t)(tokD0 + reg) * DS + n] = fast_sigmoid(acc[t][reg] + bias);
            }

            #pragma unroll
            for (int t = 0; t < 4; t++) acc[t] = (f32x4){0.f,0.f,0.f,0.f};
            mfma_group(Vf, bfA, acc);
            #pragma unroll
            for (int t = 0; t < 4; t++) {
                const int n = t * 16 + L15;
                const float bias = aB[n];
                #pragma unroll
                for (int reg = 0; reg < 4; reg++)
                    a_buf[(size_t)(tokD0 + reg) * DS + n] = fast_tanh(acc[t][reg] + bias);
            }

            #pragma unroll
            for (int t = 0; t < 4; t++) acc[t] = (f32x4){0.f,0.f,0.f,0.f};
            mfma_group(Vf, bfB, acc);
            #pragma unroll
            for (int t = 0; t < 4; t++) {
                const int n = (4 + t) * 16 + L15;
                const float bias = aB[n];
                #pragma unroll
                for (int reg = 0; reg < 4; reg++)
                    a_buf[(size_t)(tokD0 + reg) * DS + n] = fast_tanh(acc[t][reg] + bias);
            }
        } else if (tA < 1600) {
            const int tok0 = (tA - 800) * 16;
            const int tokA = tok0 + L15;
            const int tokD0 = tok0 + quad * 4;

            const bfrag* Bkm = (const bfrag*)BkmU;
            bfrag bfA[4][4], bfB[4][4];
            load_group(Bkm, 0, L, bfA);
            load_group(Bkm, 4, L, bfB);

            const int s = skill[tokA];
            const float* kp = k_emb + (size_t)s * DS + quad * 8;
            bfrag Kf[4];
            #pragma unroll
            for (int ki = 0; ki < 4; ki++) {
                const f32x4* b = (const f32x4*)(kp + ki * 32);
                Kf[ki] = mk_frag(b[0], b[1]);
            }

            f32x4 acc[4];
            #pragma unroll
            for (int t = 0; t < 4; t++) acc[t] = (f32x4){0.f,0.f,0.f,0.f};
            mfma_group(Kf, bfA, acc);
            load_group(Bkm, 8, L, bfA);
            #pragma unroll
            for (int t = 0; t < 4; t++) {
                const int n = t * 16 + L15;
                #pragma unroll
                for (int reg = 0; reg < 4; reg++)
                    kp_buf[(size_t)(tokD0 + reg) * DS + n] = acc[t][reg];
            }

            #pragma unroll
            for (int t = 0; t < 4; t++) acc[t] = (f32x4){0.f,0.f,0.f,0.f};
            mfma_group(Kf, bfB, acc);
            #pragma unroll
            for (int t = 0; t < 4; t++) {
                const int n = (4 + t) * 16 + L15;
                #pragma unroll
                for (int reg = 0; reg < 4; reg++)
                    kp_buf[(size_t)(tokD0 + reg) * DS + n] = acc[t][reg];
            }

            #pragma unroll
            for (int t = 0; t < 4; t++) acc[t] = (f32x4){0.f,0.f,0.f,0.f};
            mfma_group(Kf, bfA, acc);
            // in-wave softmax: logits c = t*16 + L15 (c<SM valid), token = tok0+quad*4+reg;
            // reduce across the 16 lanes of each quad via shfl_xor (masks 1..8 stay in-quad)
            #pragma unroll
            for (int reg = 0; reg < 4; reg++) {
                float mx = -1e30f;
                #pragma unroll
                for (int t = 0; t < 4; t++) {
                    const int c = t * 16 + L15;
                    if (c < SM) mx = fmaxf(mx, acc[t][reg]);
                }
                #pragma unroll
                for (int msk = 1; msk <= 8; msk <<= 1)
                    mx = fmaxf(mx, __shfl_xor(mx, msk));
                float ex[4], sum = 0.f;
                #pragma unroll
                for (int t = 0; t < 4; t++) {
                    const int c = t * 16 + L15;
                    ex[t] = (c < SM) ? fast_exp(acc[t][reg] - mx) : 0.f;
                    sum += ex[t];
                }
                #pragma unroll
                for (int msk = 1; msk <= 8; msk <<= 1)
                    sum += __shfl_xor(sum, msk);
                const float inv = fast_rcp(sum);
                float* wp = w_buf + (size_t)(tok0 + quad * 4 + reg) * SM;
                #pragma unroll
                for (int t = 0; t < 4; t++) {
                    const int c = t * 16 + L15;
                    if (c < SM) wp[c] = ex[t] * inv;
                }
            }
        }
    }
    grid.sync();

    // ---------- Phase B: scan, 1280 wave-tasks (b, d-half, m-group) ----------
    {
        const int bi = blockIdx.x * 5 + wv;     // waves 0..4 of each block
        if (wv < 5) {
            const int b    = bi / (2*WG2);
            const int r    = bi % (2*WG2);
            const int dh   = r / WG2;
            const int mg   = r % WG2;
            const int d    = dh*64 + L;
            const int m0   = mg * MPG2;
            const int base = b * Tn;

            float Mv[MPG2];
            #pragma unroll
            for (int m = 0; m < MPG2; m++) Mv[m] = Mv0[(size_t)(m0+m)*DS + d];

            unsigned short* pout = part16 + (size_t)mg * NTOK * DS;

            float se[4][2], sa[4][2], sw[4][2][MPG2];

            #define LOADST(ST, T)                                                      \
                { const int tc_ = ((T) < Tn) ? (T) : 0;                                \
                  _Pragma("unroll")                                                    \
                  for (int q_ = 0; q_ < 2; q_++) {                                     \
                      const int tf_ = base + tc_ + q_;                                 \
                      se[ST][q_] = e_buf[(size_t)tf_*DS + d];                          \
                      sa[ST][q_] = a_buf[(size_t)tf_*DS + d];                          \
                      _Pragma("unroll")                                                \
                      for (int m_ = 0; m_ < MPG2; m_++)                                \
                          sw[ST][q_][m_] = w_buf[(size_t)tf_*SM + m0 + m_];            \
                  } }

            LOADST(0, 0) LOADST(1, 2) LOADST(2, 4) LOADST(3, 6)

            for (int i = 0; i < 25; i++) {
                const int tb = i * 8;
                #pragma unroll
                for (int sub = 0; sub < 4; sub++) {
                    const int t0 = tb + sub * 2;
                    #pragma unroll
                    for (int q = 0; q < 2; q++) {
                        const float ev = se[sub][q], av = sa[sub][q];
                        float rd = 0.f;
                        #pragma unroll
                        for (int m = 0; m < MPG2; m++) {
                            const float wm = sw[sub][q][m];
                            rd = fmaf(wm, Mv[m], rd);                           // read uses OLD Mv
                            Mv[m] = fmaf(-wm, fmaf(ev, Mv[m], -av), Mv[m]);     // Mv*(1-w*e)+w*a
                        }
                        pout[(size_t)(base + t0 + q)*DS + d] = f2bf(rd);
                    }
                    LOADST(sub, t0 + 8)
                }
            }
            #undef LOADST
        }
    }
    grid.sync();

    // ---------- Phase C: 800 wave-tasks; combine partials + f-GEMM + pred ----------
    {
        const int tC = wv * 256 + blockIdx.x;
        if (tC < 800) {
            const int tok0 = tC * 16;
            const int tokA = tok0 + L15;
            const int tokD0 = tok0 + quad * 4;

            const bfrag* Bf0 = (const bfrag*)Bf0U;
            bfrag bfA[4][4], bfB[4][4];
            load_group(Bf0, 0, L, bfA);
            load_group(Bf0, 4, L, bfB);

            bfrag Rf[4];
            #pragma unroll
            for (int ki = 0; ki < 4; ki++) {
                const unsigned short* p0 = part16 + (size_t)tokA * DS + ki * 32 + quad * 8;
                float s0=0,s1=0,s2=0,s3=0,s4=0,s5=0,s6=0,s7=0;
                #pragma unroll
                for (int g = 0; g < WG2; g++) {
                    u32x4 v = *(const u32x4*)(p0 + (size_t)g * NTOK * DS);
                    s0 += bf2f(v[0] & 0xffffu); s1 += bf2f(v[0] >> 16);
                    s2 += bf2f(v[1] & 0xffffu); s3 += bf2f(v[1] >> 16);
                    s4 += bf2f(v[2] & 0xffffu); s5 += bf2f(v[2] >> 16);
                    s6 += bf2f(v[3] & 0xffffu); s7 += bf2f(v[3] >> 16);
                }
                Rf[ki] = mk_frag((f32x4){s0,s1,s2,s3}, (f32x4){s4,s5,s6,s7});
            }

            float f[4][8];   // [reg][nt]
            f32x4 acc[4];

            #pragma unroll
            for (int t = 0; t < 4; t++) acc[t] = (f32x4){0.f,0.f,0.f,0.f};
            mfma_group(Rf, bfA, acc);
            #pragma unroll
            for (int t = 0; t < 4; t++) {
                const int n = t * 16 + L15;
                const float fb = fB[n];
                #pragma unroll
                for (int reg = 0; reg < 4; reg++)
                    f[reg][t] = fast_tanh(acc[t][reg] + kp_buf[(size_t)(tokD0 + reg) * DS + n] + fb);
            }

            #pragma unroll
            for (int t = 0; t < 4; t++) acc[t] = (f32x4){0.f,0.f,0.f,0.f};
            mfma_group(Rf, bfB, acc);
            #pragma unroll
            for (int t = 0; t < 4; t++) {
                const int n = (4 + t) * 16 + L15;
                const float fb = fB[n];
                #pragma unroll
                for (int reg = 0; reg < 4; reg++)
                    f[reg][4 + t] = fast_tanh(acc[t][reg] + kp_buf[(size_t)(tokD0 + reg) * DS + n] + fb);
            }

            #pragma unroll
            for (int reg = 0; reg < 4; reg++) {
                const int tok = tokD0 + reg;
                const int t = tok % Tn;
                const bool act = (t < Tn - 1);
                int sn = 0, ix = 0;
                float contrib = 0.f;
                if (act) {
                    sn = skill[tok + 1];
                    ix = (sn < NUMC) ? sn : (NUMC - 1);
                    const float* pr = pW + (size_t)ix * DS + L15;
                    #pragma unroll
                    for (int nt = 0; nt < 8; nt++)
                        contrib = fmaf(f[reg][nt], pr[nt * 16], contrib);
                }
                #pragma unroll
                for (int msk = 1; msk <= 8; msk <<= 1)
                    contrib += __shfl_xor(contrib, msk);
                if (act && L15 == 0) {
                    const float val = contrib + pB[ix];
                    const float prd = (sn < NUMC) ? fast_sigmoid(val) : 0.f;
                    out[(size_t)(tok / Tn) * (Tn - 1) + t] = prd;
                }
            }
        }
    }
}

extern "C" void kernel_launch(void* const* d_in, const int* in_sizes, int n_in,
                              void* d_out, int out_size, void* d_ws, size_t ws_size,
                              hipStream_t stream)
{
    const int*   skill  = (const int*)  d_in[0];
    const int*   answer = (const int*)  d_in[1];
    const float* k_emb  = (const float*)d_in[2];
    const float* v_emb  = (const float*)d_in[3];
    const float* Mk     = (const float*)d_in[4];
    const float* Mv0    = (const float*)d_in[5];
    const float* f_W    = (const float*)d_in[6];
    const float* f_b    = (const float*)d_in[7];
    const float* p_W    = (const float*)d_in[8];
    const float* p_b    = (const float*)d_in[9];
    const float* e_W    = (const float*)d_in[10];
    const float* e_b    = (const float*)d_in[11];
    const float* a_W    = (const float*)d_in[12];
    const float* a_b    = (const float*)d_in[13];
    float* out = (float*)d_out;

    float* ws     = (float*)d_ws;
    float* w_buf  = ws;                                    // NTOK*SM
    float* e_buf  = w_buf  + (size_t)NTOK*SM;              // NTOK*DS
    float* a_buf  = e_buf  + (size_t)NTOK*DS;
    float* kp_buf = a_buf  + (size_t)NTOK*DS;
    unsigned short* part16 = (unsigned short*)(kp_buf + (size_t)NTOK*DS);  // WG2*NTOK*DS ushort
    unsigned int* BeaU = (unsigned int*)(part16 + (size_t)WG2*NTOK*DS);
    unsigned int* BkmU = BeaU + 4096 * 4;
    unsigned int* Bf0U = BkmU + 3072 * 4;
    // total ~55 MB of d_ws

    void* args[] = {
        (void*)&skill, (void*)&answer, (void*)&k_emb, (void*)&v_emb,
        (void*)&Mk, (void*)&Mv0, (void*)&f_W, (void*)&f_b,
        (void*)&p_W, (void*)&p_b, (void*)&e_W, (void*)&e_b,
        (void*)&a_W, (void*)&a_b, (void*)&out,
        (void*)&w_buf, (void*)&e_buf, (void*)&a_buf, (void*)&kp_buf,
        (void*)&part16, (void*)&BeaU, (void*)&BkmU, (void*)&Bf0U
    };
    hipLaunchCooperativeKernel((void*)fused, dim3(256), dim3(512), args, 0, stream);
}

// Round 8
// 155.314 us; speedup vs baseline: 1.4954x; 1.4954x over previous
//
#include <hip/hip_runtime.h>
#include <math.h>

#define Bsz 64
#define Tn 200
#define NUMC 2000
#define DS 128
#define SM 50
#define NTOK (Bsz*Tn)
#define WG2 10       // m-groups in scan
#define MPG2 5       // m per group (WG2*MPG2 == SM)

typedef __attribute__((ext_vector_type(8))) short bfrag;
typedef __attribute__((ext_vector_type(4))) float f32x4;
typedef __attribute__((ext_vector_type(2))) float f32x2;
typedef __attribute__((ext_vector_type(4))) unsigned int u32x4;

__device__ __forceinline__ unsigned short f2bf(float x) {
    unsigned int u = __builtin_bit_cast(unsigned int, x);
    u = u + 0x7fffu + ((u >> 16) & 1u);   // RNE
    return (unsigned short)(u >> 16);
}
__device__ __forceinline__ unsigned int pack2(float a, float b) {
    return (unsigned int)f2bf(a) | ((unsigned int)f2bf(b) << 16);
}
__device__ __forceinline__ bfrag mk_frag(f32x4 x, f32x4 y) {
    u32x4 t;
    t[0] = pack2(x[0], x[1]); t[1] = pack2(x[2], x[3]);
    t[2] = pack2(y[0], y[1]); t[3] = pack2(y[2], y[3]);
    return __builtin_bit_cast(bfrag, t);
}

// fast transcendentals: v_exp_f32 / v_rcp_f32 (~1e-6 rel err, invisible at bf16 grade)
__device__ __forceinline__ float fast_exp(float x)  { return __builtin_amdgcn_exp2f(x * 1.44269504f); }
__device__ __forceinline__ float fast_rcp(float x)  { return __builtin_amdgcn_rcpf(x); }
__device__ __forceinline__ float fast_sigmoid(float x) { return fast_rcp(1.f + fast_exp(-x)); }
__device__ __forceinline__ float fast_tanh(float x) { return 1.f - 2.f * fast_rcp(fast_exp(2.f * x) + 1.f); }

__device__ __forceinline__ void load_group(const bfrag* __restrict__ B, int nt0, int L, bfrag bf[4][4]) {
    #pragma unroll
    for (int t = 0; t < 4; t++)
        #pragma unroll
        for (int ki = 0; ki < 4; ki++)
            bf[t][ki] = B[(size_t)((nt0 + t) * 4 + ki) * 64 + L];
}
__device__ __forceinline__ void mfma_group(const bfrag A[4], const bfrag bf[4][4], f32x4 acc[4]) {
    #pragma unroll
    for (int ki = 0; ki < 4; ki++)
        #pragma unroll
        for (int t = 0; t < 4; t++)
            acc[t] = __builtin_amdgcn_mfma_f32_16x16x32_bf16(A[ki], bf[t][ki], acc[t], 0, 0, 0);
}

// ---------------- K0: cast weights into MFMA b-frag block layout (as R4) ----------------
__global__ __launch_bounds__(256) void k0_cast(
    const float* __restrict__ eW, const float* __restrict__ aW,
    const float* __restrict__ fW, const float* __restrict__ Mk,
    unsigned int* __restrict__ BeaU, unsigned int* __restrict__ BkmU,
    unsigned int* __restrict__ Bf0U)
{
    const int g = blockIdx.x * 256 + threadIdx.x;
    if (g >= 9216) return;
    int gm, mat;
    unsigned int* dst;
    if (g < 4096)      { mat = 0; gm = g;        dst = BeaU; }
    else if (g < 7168) { mat = 1; gm = g - 4096; dst = BkmU; }
    else               { mat = 2; gm = g - 7168; dst = Bf0U; }
    const int nt = gm >> 8, r = gm & 255, ki = r >> 6, L = r & 63;
    const int n = nt * 16 + (L & 15);
    const int k = ki * 32 + (L >> 4) * 8;

    const float* src = nullptr;
    if (mat == 0) {
        src = (n < 128) ? (eW + (size_t)n * DS + k) : (aW + (size_t)(n - 128) * DS + k);
    } else if (mat == 1) {
        if (n < 128)           src = fW + (size_t)n * (2 * DS) + DS + k;
        else if (n < 128 + SM) src = Mk + (size_t)(n - 128) * DS + k;
    } else {
        src = fW + (size_t)n * (2 * DS) + k;
    }
    float v[8];
    #pragma unroll
    for (int j = 0; j < 8; j++) v[j] = src ? src[j] : 0.f;
    u32x4 o;
    o[0] = pack2(v[0], v[1]); o[1] = pack2(v[2], v[3]);
    o[2] = pack2(v[4], v[5]); o[3] = pack2(v[6], v[7]);
    ((u32x4*)dst)[gm] = o;
}

// ---------------- K1: 1-wave blocks; bid<800 EA wave, else KM wave ----------------
// EA writes ea_buf interleaved [tok][2d]=e,[2d+1]=a.  KM writes kp_buf + w2[tok][mg][8].
__global__ __launch_bounds__(64) void k1_gemm(
    const int* __restrict__ skill, const int* __restrict__ answer,
    const float* __restrict__ k_emb, const float* __restrict__ v_emb,
    const unsigned int* __restrict__ BeaU, const unsigned int* __restrict__ BkmU,
    const float* __restrict__ eB, const float* __restrict__ aB,
    float* __restrict__ w2, float* __restrict__ ea_buf, float* __restrict__ kp_buf)
{
    const int bid = blockIdx.x;
    const int L = threadIdx.x, L15 = L & 15, quad = L >> 4;

    if (bid < NTOK/16) {
        const int tok0 = bid * 16;
        const int tokA = tok0 + L15;
        const int tokD0 = tok0 + quad * 4;

        const bfrag* Bea = (const bfrag*)BeaU;
        bfrag bfA[4][4], bfB[4][4];
        load_group(Bea, 0, L, bfA);
        load_group(Bea, 4, L, bfB);

        const int s  = skill[tokA];
        const int an = answer[tokA];
        const int ax = (an == 2) ? 1 : an;
        const float* vp = v_emb + ((size_t)(s + NUMC * ax)) * DS + quad * 8;
        bfrag Vf[4];
        #pragma unroll
        for (int ki = 0; ki < 4; ki++) {
            const f32x4* a = (const f32x4*)(vp + ki * 32);
            Vf[ki] = mk_frag(a[0], a[1]);
        }

        f32x4 acc[4];
        #pragma unroll
        for (int t = 0; t < 4; t++) acc[t] = (f32x4){0.f,0.f,0.f,0.f};
        mfma_group(Vf, bfA, acc);
        load_group(Bea, 8, L, bfA);
        #pragma unroll
        for (int t = 0; t < 4; t++) {
            const int n = t * 16 + L15;
            const float bias = eB[n];
            #pragma unroll
            for (int reg = 0; reg < 4; reg++)
                ea_buf[(size_t)(tokD0 + reg) * (2*DS) + 2*n] = fast_sigmoid(acc[t][reg] + bias);
        }

        #pragma unroll
        for (int t = 0; t < 4; t++) acc[t] = (f32x4){0.f,0.f,0.f,0.f};
        mfma_group(Vf, bfB, acc);
        load_group(Bea, 12, L, bfB);
        #pragma unroll
        for (int t = 0; t < 4; t++) {
            const int n = (4 + t) * 16 + L15;
            const float bias = eB[n];
            #pragma unroll
            for (int reg = 0; reg < 4; reg++)
                ea_buf[(size_t)(tokD0 + reg) * (2*DS) + 2*n] = fast_sigmoid(acc[t][reg] + bias);
        }

        #pragma unroll
        for (int t = 0; t < 4; t++) acc[t] = (f32x4){0.f,0.f,0.f,0.f};
        mfma_group(Vf, bfA, acc);
        #pragma unroll
        for (int t = 0; t < 4; t++) {
            const int n = t * 16 + L15;
            const float bias = aB[n];
            #pragma unroll
            for (int reg = 0; reg < 4; reg++)
                ea_buf[(size_t)(tokD0 + reg) * (2*DS) + 2*n + 1] = fast_tanh(acc[t][reg] + bias);
        }

        #pragma unroll
        for (int t = 0; t < 4; t++) acc[t] = (f32x4){0.f,0.f,0.f,0.f};
        mfma_group(Vf, bfB, acc);
        #pragma unroll
        for (int t = 0; t < 4; t++) {
            const int n = (4 + t) * 16 + L15;
            const float bias = aB[n];
            #pragma unroll
            for (int reg = 0; reg < 4; reg++)
                ea_buf[(size_t)(tokD0 + reg) * (2*DS) + 2*n + 1] = fast_tanh(acc[t][reg] + bias);
        }
    } else {
        const int tok0 = (bid - NTOK/16) * 16;
        const int tokA = tok0 + L15;
        const int tokD0 = tok0 + quad * 4;

        const bfrag* Bkm = (const bfrag*)BkmU;
        bfrag bfA[4][4], bfB[4][4];
        load_group(Bkm, 0, L, bfA);
        load_group(Bkm, 4, L, bfB);

        const int s = skill[tokA];
        const float* kp = k_emb + (size_t)s * DS + quad * 8;
        bfrag Kf[4];
        #pragma unroll
        for (int ki = 0; ki < 4; ki++) {
            const f32x4* b = (const f32x4*)(kp + ki * 32);
            Kf[ki] = mk_frag(b[0], b[1]);
        }

        f32x4 acc[4];
        #pragma unroll
        for (int t = 0; t < 4; t++) acc[t] = (f32x4){0.f,0.f,0.f,0.f};
        mfma_group(Kf, bfA, acc);
        load_group(Bkm, 8, L, bfA);
        #pragma unroll
        for (int t = 0; t < 4; t++) {
            const int n = t * 16 + L15;
            #pragma unroll
            for (int reg = 0; reg < 4; reg++)
                kp_buf[(size_t)(tokD0 + reg) * DS + n] = acc[t][reg];
        }

        #pragma unroll
        for (int t = 0; t < 4; t++) acc[t] = (f32x4){0.f,0.f,0.f,0.f};
        mfma_group(Kf, bfB, acc);
        #pragma unroll
        for (int t = 0; t < 4; t++) {
            const int n = (4 + t) * 16 + L15;
            #pragma unroll
            for (int reg = 0; reg < 4; reg++)
                kp_buf[(size_t)(tokD0 + reg) * DS + n] = acc[t][reg];
        }

        #pragma unroll
        for (int t = 0; t < 4; t++) acc[t] = (f32x4){0.f,0.f,0.f,0.f};
        mfma_group(Kf, bfA, acc);
        // in-wave softmax over c = t*16 + L15 (valid c<SM); token = tok0 + quad*4 + reg.
        // shfl_xor masks 1..8 stay within each 16-lane quad group.
        #pragma unroll
        for (int reg = 0; reg < 4; reg++) {
            float mx = -1e30f;
            #pragma unroll
            for (int t = 0; t < 4; t++) {
                const int c = t * 16 + L15;
                if (c < SM) mx = fmaxf(mx, acc[t][reg]);
            }
            #pragma unroll
            for (int msk = 1; msk <= 8; msk <<= 1)
                mx = fmaxf(mx, __shfl_xor(mx, msk));
            float ex[4], sum = 0.f;
            #pragma unroll
            for (int t = 0; t < 4; t++) {
                const int c = t * 16 + L15;
                ex[t] = (c < SM) ? fast_exp(acc[t][reg] - mx) : 0.f;
                sum += ex[t];
            }
            #pragma unroll
            for (int msk = 1; msk <= 8; msk <<= 1)
                sum += __shfl_xor(sum, msk);
            const float inv = fast_rcp(sum);
            float* wp = w2 + (size_t)(tok0 + quad * 4 + reg) * 80;
            #pragma unroll
            for (int t = 0; t < 4; t++) {
                const int c = t * 16 + L15;
                if (c < SM) wp[(c / MPG2) * 8 + (c % MPG2)] = ex[t] * inv;
            }
        }
    }
}

// ---------------- K2: scan; 1-wave blocks (b, d-half, m-group); 16-step prefetch ring ----------------
__global__ __launch_bounds__(64, 2) void k2_scan(
    const float* __restrict__ w2, const float* __restrict__ ea_buf,
    const float* __restrict__ Mv0, float* __restrict__ part_buf)
{
    const int bi   = blockIdx.x;
    const int b    = bi / (2*WG2);
    const int r    = bi % (2*WG2);
    const int dh   = r / WG2;
    const int mg   = r % WG2;
    const int lane = threadIdx.x;
    const int d    = dh*64 + lane;
    const int m0   = mg * MPG2;
    const int base = b * Tn;

    float Mv[MPG2];
    #pragma unroll
    for (int m = 0; m < MPG2; m++) Mv[m] = Mv0[(size_t)(m0+m)*DS + d];

    float* pout = part_buf + (size_t)mg * NTOK * DS;

    // ring: 8 stages x 2 steps = 16 timesteps in flight (~960 cyc of latency cover)
    f32x2 rea[8][2];
    float rw[8][2][MPG2];

    #define LOADST(ST, T)                                                          \
        { const int tc_ = ((T) < Tn) ? (T) : 0;                                    \
          _Pragma("unroll")                                                        \
          for (int q_ = 0; q_ < 2; q_++) {                                         \
              const int tf_ = base + tc_ + q_;                                     \
              rea[ST][q_] = *(const f32x2*)(ea_buf + (size_t)tf_*(2*DS) + 2*d);    \
              const float* wp_ = w2 + (size_t)tf_*80 + mg*8;                       \
              f32x4 w4_ = *(const f32x4*)wp_;                                      \
              rw[ST][q_][0]=w4_[0]; rw[ST][q_][1]=w4_[1];                          \
              rw[ST][q_][2]=w4_[2]; rw[ST][q_][3]=w4_[3];                          \
              rw[ST][q_][4]=wp_[4];                                               \
          } }

    #define STAGE(ST, T0)                                                          \
        { _Pragma("unroll")                                                        \
          for (int q = 0; q < 2; q++) {                                            \
              const float ev = rea[ST][q][0], av = rea[ST][q][1];                  \
              float rd = 0.f;                                                      \
              _Pragma("unroll")                                                    \
              for (int m = 0; m < MPG2; m++) {                                     \
                  const float wm = rw[ST][q][m];                                   \
                  rd = fmaf(wm, Mv[m], rd);                       /* old Mv */     \
                  Mv[m] = fmaf(-wm, fmaf(ev, Mv[m], -av), Mv[m]); /* update */     \
              }                                                                    \
              pout[(size_t)(base + (T0) + q)*DS + d] = rd;                         \
          }                                                                        \
          LOADST(ST, (T0) + 16) }

    LOADST(0, 0) LOADST(1, 2) LOADST(2, 4) LOADST(3, 6)
    LOADST(4, 8) LOADST(5, 10) LOADST(6, 12) LOADST(7, 14)

    for (int blk = 0; blk < 12; blk++) {
        const int t0 = blk * 16;
        STAGE(0, t0)      STAGE(1, t0 + 2)  STAGE(2, t0 + 4)  STAGE(3, t0 + 6)
        STAGE(4, t0 + 8)  STAGE(5, t0 + 10) STAGE(6, t0 + 12) STAGE(7, t0 + 14)
    }
    STAGE(0, 192) STAGE(1, 194) STAGE(2, 196) STAGE(3, 198)
    #undef STAGE
    #undef LOADST
}

// ---------------- K3: 1-wave blocks; combine fp32 partials + f-GEMM + pred (as R4) ----------------
__global__ __launch_bounds__(64) void k3_gemm(
    const float* __restrict__ part_buf, const float* __restrict__ kp_buf,
    const unsigned int* __restrict__ Bf0U, const float* __restrict__ fB,
    const float* __restrict__ pW, const float* __restrict__ pB,
    const int* __restrict__ skill, float* __restrict__ out)
{
    const int L = threadIdx.x, L15 = L & 15, quad = L >> 4;
    const int tok0 = blockIdx.x * 16;
    const int tokA = tok0 + L15;
    const int tokD0 = tok0 + quad * 4;

    const bfrag* Bf0 = (const bfrag*)Bf0U;
    bfrag bfA[4][4], bfB[4][4];
    load_group(Bf0, 0, L, bfA);
    load_group(Bf0, 4, L, bfB);

    bfrag Rf[4];
    #pragma unroll
    for (int ki = 0; ki < 4; ki++) {
        const float* p0 = part_buf + (size_t)tokA * DS + ki * 32 + quad * 8;
        f32x4 x = (f32x4){0.f,0.f,0.f,0.f}, y = (f32x4){0.f,0.f,0.f,0.f};
        #pragma unroll
        for (int g = 0; g < WG2; g++) {
            const f32x4* q4 = (const f32x4*)(p0 + (size_t)g * NTOK * DS);
            x = x + q4[0]; y = y + q4[1];
        }
        Rf[ki] = mk_frag(x, y);
    }

    float f[4][8];   // [reg][nt]
    f32x4 acc[4];

    #pragma unroll
    for (int t = 0; t < 4; t++) acc[t] = (f32x4){0.f,0.f,0.f,0.f};
    mfma_group(Rf, bfA, acc);
    #pragma unroll
    for (int t = 0; t < 4; t++) {
        const int n = t * 16 + L15;
        const float fb = fB[n];
        #pragma unroll
        for (int reg = 0; reg < 4; reg++)
            f[reg][t] = fast_tanh(acc[t][reg] + kp_buf[(size_t)(tokD0 + reg) * DS + n] + fb);
    }

    #pragma unroll
    for (int t = 0; t < 4; t++) acc[t] = (f32x4){0.f,0.f,0.f,0.f};
    mfma_group(Rf, bfB, acc);
    #pragma unroll
    for (int t = 0; t < 4; t++) {
        const int n = (4 + t) * 16 + L15;
        const float fb = fB[n];
        #pragma unroll
        for (int reg = 0; reg < 4; reg++)
            f[reg][4 + t] = fast_tanh(acc[t][reg] + kp_buf[(size_t)(tokD0 + reg) * DS + n] + fb);
    }

    #pragma unroll
    for (int reg = 0; reg < 4; reg++) {
        const int tok = tokD0 + reg;
        const int t = tok % Tn;
        const bool act = (t < Tn - 1);
        int sn = 0, ix = 0;
        float contrib = 0.f;
        if (act) {
            sn = skill[tok + 1];
            ix = (sn < NUMC) ? sn : (NUMC - 1);
            const float* pr = pW + (size_t)ix * DS + L15;
            #pragma unroll
            for (int nt = 0; nt < 8; nt++)
                contrib = fmaf(f[reg][nt], pr[nt * 16], contrib);
        }
        #pragma unroll
        for (int msk = 1; msk <= 8; msk <<= 1)
            contrib += __shfl_xor(contrib, msk);
        if (act && L15 == 0) {
            const float val = contrib + pB[ix];
            const float prd = (sn < NUMC) ? fast_sigmoid(val) : 0.f;
            out[(size_t)(tok / Tn) * (Tn - 1) + t] = prd;
        }
    }
}

extern "C" void kernel_launch(void* const* d_in, const int* in_sizes, int n_in,
                              void* d_out, int out_size, void* d_ws, size_t ws_size,
                              hipStream_t stream)
{
    const int*   skill  = (const int*)  d_in[0];
    const int*   answer = (const int*)  d_in[1];
    const float* k_emb  = (const float*)d_in[2];
    const float* v_emb  = (const float*)d_in[3];
    const float* Mk     = (const float*)d_in[4];
    const float* Mv0    = (const float*)d_in[5];
    const float* f_W    = (const float*)d_in[6];
    const float* f_b    = (const float*)d_in[7];
    const float* p_W    = (const float*)d_in[8];
    const float* p_b    = (const float*)d_in[9];
    const float* e_W    = (const float*)d_in[10];
    const float* e_b    = (const float*)d_in[11];
    const float* a_W    = (const float*)d_in[12];
    const float* a_b    = (const float*)d_in[13];
    float* out = (float*)d_out;

    float* ws       = (float*)d_ws;
    float* w2       = ws;                                   // NTOK*80
    float* ea_buf   = w2     + (size_t)NTOK*80;             // NTOK*2*DS
    float* kp_buf   = ea_buf + (size_t)NTOK*2*DS;           // NTOK*DS
    float* part_buf = kp_buf + (size_t)NTOK*DS;             // WG2*NTOK*DS
    unsigned int* BeaU = (unsigned int*)(part_buf + (size_t)WG2*NTOK*DS);
    unsigned int* BkmU = BeaU + 4096 * 4;
    unsigned int* Bf0U = BkmU + 3072 * 4;
    // total ~90 MB of d_ws

    k0_cast<<<36, 256, 0, stream>>>(e_W, a_W, f_W, Mk, BeaU, BkmU, Bf0U);
    k1_gemm<<<2*(NTOK/16), 64, 0, stream>>>(skill, answer, k_emb, v_emb,
        BeaU, BkmU, e_b, a_b, w2, ea_buf, kp_buf);
    k2_scan<<<Bsz*2*WG2, 64, 0, stream>>>(w2, ea_buf, Mv0, part_buf);
    k3_gemm<<<NTOK/16, 64, 0, stream>>>(part_buf, kp_buf, Bf0U, f_b,
        p_W, p_b, skill, out);
}

// Round 9
// 151.132 us; speedup vs baseline: 1.5367x; 1.0277x over previous
//
#include <hip/hip_runtime.h>
#include <math.h>

#define Bsz 64
#define Tn 200
#define NUMC 2000
#define DS 128
#define SM 50
#define NTOK (Bsz*Tn)
#define WG2 10       // m-groups in scan
#define MPG2 5       // m per group (WG2*MPG2 == SM)

typedef __attribute__((ext_vector_type(8))) short bfrag;
typedef __attribute__((ext_vector_type(4))) float f32x4;
typedef __attribute__((ext_vector_type(4))) unsigned int u32x4;

__device__ __forceinline__ unsigned short f2bf(float x) {
    unsigned int u = __builtin_bit_cast(unsigned int, x);
    u = u + 0x7fffu + ((u >> 16) & 1u);   // RNE
    return (unsigned short)(u >> 16);
}
__device__ __forceinline__ unsigned int pack2(float a, float b) {
    return (unsigned int)f2bf(a) | ((unsigned int)f2bf(b) << 16);
}
__device__ __forceinline__ float bf2f(unsigned int u) {
    return __builtin_bit_cast(float, u << 16);
}
__device__ __forceinline__ bfrag mk_frag(f32x4 x, f32x4 y) {
    u32x4 t;
    t[0] = pack2(x[0], x[1]); t[1] = pack2(x[2], x[3]);
    t[2] = pack2(y[0], y[1]); t[3] = pack2(y[2], y[3]);
    return __builtin_bit_cast(bfrag, t);
}

// fast transcendentals: v_exp_f32 / v_rcp_f32 (~1e-6 rel err, invisible at bf16 grade)
__device__ __forceinline__ float fast_exp(float x)  { return __builtin_amdgcn_exp2f(x * 1.44269504f); }
__device__ __forceinline__ float fast_rcp(float x)  { return __builtin_amdgcn_rcpf(x); }
__device__ __forceinline__ float fast_sigmoid(float x) { return fast_rcp(1.f + fast_exp(-x)); }
__device__ __forceinline__ float fast_tanh(float x) { return 1.f - 2.f * fast_rcp(fast_exp(2.f * x) + 1.f); }

__device__ __forceinline__ void load_group(const bfrag* __restrict__ B, int nt0, int L, bfrag bf[4][4]) {
    #pragma unroll
    for (int t = 0; t < 4; t++)
        #pragma unroll
        for (int ki = 0; ki < 4; ki++)
            bf[t][ki] = B[(size_t)((nt0 + t) * 4 + ki) * 64 + L];
}
__device__ __forceinline__ void mfma_group(const bfrag A[4], const bfrag bf[4][4], f32x4 acc[4]) {
    #pragma unroll
    for (int ki = 0; ki < 4; ki++)
        #pragma unroll
        for (int t = 0; t < 4; t++)
            acc[t] = __builtin_amdgcn_mfma_f32_16x16x32_bf16(A[ki], bf[t][ki], acc[t], 0, 0, 0);
}

// ---------------- K0: cast weights into MFMA b-frag block layout ----------------
__global__ __launch_bounds__(256) void k0_cast(
    const float* __restrict__ eW, const float* __restrict__ aW,
    const float* __restrict__ fW, const float* __restrict__ Mk,
    unsigned int* __restrict__ BeaU, unsigned int* __restrict__ BkmU,
    unsigned int* __restrict__ Bf0U)
{
    const int g = blockIdx.x * 256 + threadIdx.x;
    if (g >= 9216) return;
    int gm, mat;
    unsigned int* dst;
    if (g < 4096)      { mat = 0; gm = g;        dst = BeaU; }
    else if (g < 7168) { mat = 1; gm = g - 4096; dst = BkmU; }
    else               { mat = 2; gm = g - 7168; dst = Bf0U; }
    const int nt = gm >> 8, r = gm & 255, ki = r >> 6, L = r & 63;
    const int n = nt * 16 + (L & 15);
    const int k = ki * 32 + (L >> 4) * 8;

    const float* src = nullptr;
    if (mat == 0) {
        src = (n < 128) ? (eW + (size_t)n * DS + k) : (aW + (size_t)(n - 128) * DS + k);
    } else if (mat == 1) {
        if (n < 128)           src = fW + (size_t)n * (2 * DS) + DS + k;
        else if (n < 128 + SM) src = Mk + (size_t)(n - 128) * DS + k;
    } else {
        src = fW + (size_t)n * (2 * DS) + k;
    }
    float v[8];
    #pragma unroll
    for (int j = 0; j < 8; j++) v[j] = src ? src[j] : 0.f;
    u32x4 o;
    o[0] = pack2(v[0], v[1]); o[1] = pack2(v[2], v[3]);
    o[2] = pack2(v[4], v[5]); o[3] = pack2(v[6], v[7]);
    ((u32x4*)dst)[gm] = o;
}

// ---------------- K1: 1-wave blocks; bid<800 EA wave, else KM wave ----------------
// EA: all 4 acc groups held, then e,a packed bf16x2 -> ea32[tok*DS + n].
// KM: kp_buf fp32 + in-wave softmax -> w2[tok][mg][8].
__global__ __launch_bounds__(64) void k1_gemm(
    const int* __restrict__ skill, const int* __restrict__ answer,
    const float* __restrict__ k_emb, const float* __restrict__ v_emb,
    const unsigned int* __restrict__ BeaU, const unsigned int* __restrict__ BkmU,
    const float* __restrict__ eB, const float* __restrict__ aB,
    float* __restrict__ w2, unsigned int* __restrict__ ea32, float* __restrict__ kp_buf)
{
    const int bid = blockIdx.x;
    const int L = threadIdx.x, L15 = L & 15, quad = L >> 4;

    if (bid < NTOK/16) {
        const int tok0 = bid * 16;
        const int tokA = tok0 + L15;
        const int tokD0 = tok0 + quad * 4;

        const bfrag* Bea = (const bfrag*)BeaU;
        bfrag bfA[4][4], bfB[4][4];
        load_group(Bea, 0, L, bfA);
        load_group(Bea, 4, L, bfB);

        const int s  = skill[tokA];
        const int an = answer[tokA];
        const int ax = (an == 2) ? 1 : an;
        const float* vp = v_emb + ((size_t)(s + NUMC * ax)) * DS + quad * 8;
        bfrag Vf[4];
        #pragma unroll
        for (int ki = 0; ki < 4; ki++) {
            const f32x4* a = (const f32x4*)(vp + ki * 32);
            Vf[ki] = mk_frag(a[0], a[1]);
        }

        // acc0: e rows 0-63, acc1: e rows 64-127, acc2: a rows 0-63, acc3: a rows 64-127
        f32x4 acc0[4], acc1[4], acc2[4], acc3[4];
        #pragma unroll
        for (int t = 0; t < 4; t++) {
            acc0[t] = (f32x4){0.f,0.f,0.f,0.f}; acc1[t] = (f32x4){0.f,0.f,0.f,0.f};
            acc2[t] = (f32x4){0.f,0.f,0.f,0.f}; acc3[t] = (f32x4){0.f,0.f,0.f,0.f};
        }
        mfma_group(Vf, bfA, acc0);
        load_group(Bea, 8, L, bfA);
        mfma_group(Vf, bfB, acc1);
        load_group(Bea, 12, L, bfB);
        mfma_group(Vf, bfA, acc2);
        mfma_group(Vf, bfB, acc3);

        #pragma unroll
        for (int t = 0; t < 4; t++) {
            const int n0 = t * 16 + L15;        // rows 0-63
            const int n1 = n0 + 64;             // rows 64-127
            const float eb0 = eB[n0], ab0 = aB[n0];
            const float eb1 = eB[n1], ab1 = aB[n1];
            #pragma unroll
            for (int reg = 0; reg < 4; reg++) {
                const size_t tok = (size_t)(tokD0 + reg);
                ea32[tok * DS + n0] = pack2(fast_sigmoid(acc0[t][reg] + eb0),
                                            fast_tanh   (acc2[t][reg] + ab0));
                ea32[tok * DS + n1] = pack2(fast_sigmoid(acc1[t][reg] + eb1),
                                            fast_tanh   (acc3[t][reg] + ab1));
            }
        }
    } else {
        const int tok0 = (bid - NTOK/16) * 16;
        const int tokA = tok0 + L15;
        const int tokD0 = tok0 + quad * 4;

        const bfrag* Bkm = (const bfrag*)BkmU;
        bfrag bfA[4][4], bfB[4][4];
        load_group(Bkm, 0, L, bfA);
        load_group(Bkm, 4, L, bfB);

        const int s = skill[tokA];
        const float* kp = k_emb + (size_t)s * DS + quad * 8;
        bfrag Kf[4];
        #pragma unroll
        for (int ki = 0; ki < 4; ki++) {
            const f32x4* b = (const f32x4*)(kp + ki * 32);
            Kf[ki] = mk_frag(b[0], b[1]);
        }

        f32x4 acc[4];
        #pragma unroll
        for (int t = 0; t < 4; t++) acc[t] = (f32x4){0.f,0.f,0.f,0.f};
        mfma_group(Kf, bfA, acc);
        load_group(Bkm, 8, L, bfA);
        #pragma unroll
        for (int t = 0; t < 4; t++) {
            const int n = t * 16 + L15;
            #pragma unroll
            for (int reg = 0; reg < 4; reg++)
                kp_buf[(size_t)(tokD0 + reg) * DS + n] = acc[t][reg];
        }

        #pragma unroll
        for (int t = 0; t < 4; t++) acc[t] = (f32x4){0.f,0.f,0.f,0.f};
        mfma_group(Kf, bfB, acc);
        #pragma unroll
        for (int t = 0; t < 4; t++) {
            const int n = (4 + t) * 16 + L15;
            #pragma unroll
            for (int reg = 0; reg < 4; reg++)
                kp_buf[(size_t)(tokD0 + reg) * DS + n] = acc[t][reg];
        }

        #pragma unroll
        for (int t = 0; t < 4; t++) acc[t] = (f32x4){0.f,0.f,0.f,0.f};
        mfma_group(Kf, bfA, acc);
        // in-wave softmax over c = t*16 + L15 (valid c<SM); token = tok0 + quad*4 + reg.
        #pragma unroll
        for (int reg = 0; reg < 4; reg++) {
            float mx = -1e30f;
            #pragma unroll
            for (int t = 0; t < 4; t++) {
                const int c = t * 16 + L15;
                if (c < SM) mx = fmaxf(mx, acc[t][reg]);
            }
            #pragma unroll
            for (int msk = 1; msk <= 8; msk <<= 1)
                mx = fmaxf(mx, __shfl_xor(mx, msk));
            float ex[4], sum = 0.f;
            #pragma unroll
            for (int t = 0; t < 4; t++) {
                const int c = t * 16 + L15;
                ex[t] = (c < SM) ? fast_exp(acc[t][reg] - mx) : 0.f;
                sum += ex[t];
            }
            #pragma unroll
            for (int msk = 1; msk <= 8; msk <<= 1)
                sum += __shfl_xor(sum, msk);
            const float inv = fast_rcp(sum);
            float* wp = w2 + (size_t)(tok0 + quad * 4 + reg) * 80;
            #pragma unroll
            for (int t = 0; t < 4; t++) {
                const int c = t * 16 + L15;
                if (c < SM) wp[(c / MPG2) * 8 + (c % MPG2)] = ex[t] * inv;
            }
        }
    }
}

// ---------------- K2: scan; 1-wave blocks (b, d-half, m-group); packed ea, bf16 partials ----------------
__global__ __launch_bounds__(64, 2) void k2_scan(
    const float* __restrict__ w2, const unsigned int* __restrict__ ea32,
    const float* __restrict__ Mv0, unsigned short* __restrict__ part16)
{
    const int bi   = blockIdx.x;
    const int b    = bi / (2*WG2);
    const int r    = bi % (2*WG2);
    const int dh   = r / WG2;
    const int mg   = r % WG2;
    const int lane = threadIdx.x;
    const int d    = dh*64 + lane;
    const int m0   = mg * MPG2;
    const int base = b * Tn;

    float Mv[MPG2];
    #pragma unroll
    for (int m = 0; m < MPG2; m++) Mv[m] = Mv0[(size_t)(m0+m)*DS + d];

    unsigned short* pout = part16 + (size_t)mg * NTOK * DS;

    // ring: 8 stages x 2 steps (compiler will schedule loads as it sees fit)
    unsigned int rea[8][2];
    float rw[8][2][MPG2];

    #define LOADST(ST, T)                                                          \
        { const int tc_ = ((T) < Tn) ? (T) : 0;                                    \
          _Pragma("unroll")                                                        \
          for (int q_ = 0; q_ < 2; q_++) {                                         \
              const int tf_ = base + tc_ + q_;                                     \
              rea[ST][q_] = ea32[(size_t)tf_*DS + d];                              \
              const float* wp_ = w2 + (size_t)tf_*80 + mg*8;                       \
              f32x4 w4_ = *(const f32x4*)wp_;                                      \
              rw[ST][q_][0]=w4_[0]; rw[ST][q_][1]=w4_[1];                          \
              rw[ST][q_][2]=w4_[2]; rw[ST][q_][3]=w4_[3];                          \
              rw[ST][q_][4]=wp_[4];                                               \
          } }

    #define STAGE(ST, T0)                                                          \
        { _Pragma("unroll")                                                        \
          for (int q = 0; q < 2; q++) {                                            \
              const unsigned int v_ = rea[ST][q];                                  \
              const float ev = bf2f(v_ & 0xffffu), av = bf2f(v_ >> 16);            \
              float rd = 0.f;                                                      \
              _Pragma("unroll")                                                    \
              for (int m = 0; m < MPG2; m++) {                                     \
                  const float wm = rw[ST][q][m];                                   \
                  rd = fmaf(wm, Mv[m], rd);                       /* old Mv */     \
                  Mv[m] = fmaf(-wm, fmaf(ev, Mv[m], -av), Mv[m]); /* update */     \
              }                                                                    \
              pout[(size_t)(base + (T0) + q)*DS + d] = f2bf(rd);                   \
          }                                                                        \
          LOADST(ST, (T0) + 16) }

    LOADST(0, 0) LOADST(1, 2) LOADST(2, 4) LOADST(3, 6)
    LOADST(4, 8) LOADST(5, 10) LOADST(6, 12) LOADST(7, 14)

    for (int blk = 0; blk < 12; blk++) {
        const int t0 = blk * 16;
        STAGE(0, t0)      STAGE(1, t0 + 2)  STAGE(2, t0 + 4)  STAGE(3, t0 + 6)
        STAGE(4, t0 + 8)  STAGE(5, t0 + 10) STAGE(6, t0 + 12) STAGE(7, t0 + 14)
    }
    STAGE(0, 192) STAGE(1, 194) STAGE(2, 196) STAGE(3, 198)
    #undef STAGE
    #undef LOADST
}

// ---------------- K3: 1-wave blocks; combine bf16 partials + f-GEMM + pred ----------------
__global__ __launch_bounds__(64) void k3_gemm(
    const unsigned short* __restrict__ part16, const float* __restrict__ kp_buf,
    const unsigned int* __restrict__ Bf0U, const float* __restrict__ fB,
    const float* __restrict__ pW, const float* __restrict__ pB,
    const int* __restrict__ skill, float* __restrict__ out)
{
    const int L = threadIdx.x, L15 = L & 15, quad = L >> 4;
    const int tok0 = blockIdx.x * 16;
    const int tokA = tok0 + L15;
    const int tokD0 = tok0 + quad * 4;

    const bfrag* Bf0 = (const bfrag*)Bf0U;
    bfrag bfA[4][4], bfB[4][4];
    load_group(Bf0, 0, L, bfA);
    load_group(Bf0, 4, L, bfB);

    // A-frags: reads = sum of WG2 bf16 partials, repacked to bf16
    bfrag Rf[4];
    #pragma unroll
    for (int ki = 0; ki < 4; ki++) {
        const unsigned short* p0 = part16 + (size_t)tokA * DS + ki * 32 + quad * 8;
        float s0=0,s1=0,s2=0,s3=0,s4=0,s5=0,s6=0,s7=0;
        #pragma unroll
        for (int g = 0; g < WG2; g++) {
            u32x4 v = *(const u32x4*)(p0 + (size_t)g * NTOK * DS);
            s0 += bf2f(v[0] & 0xffffu); s1 += bf2f(v[0] >> 16);
            s2 += bf2f(v[1] & 0xffffu); s3 += bf2f(v[1] >> 16);
            s4 += bf2f(v[2] & 0xffffu); s5 += bf2f(v[2] >> 16);
            s6 += bf2f(v[3] & 0xffffu); s7 += bf2f(v[3] >> 16);
        }
        Rf[ki] = mk_frag((f32x4){s0,s1,s2,s3}, (f32x4){s4,s5,s6,s7});
    }

    float f[4][8];   // [reg][nt]
    f32x4 acc[4];

    #pragma unroll
    for (int t = 0; t < 4; t++) acc[t] = (f32x4){0.f,0.f,0.f,0.f};
    mfma_group(Rf, bfA, acc);
    #pragma unroll
    for (int t = 0; t < 4; t++) {
        const int n = t * 16 + L15;
        const float fb = fB[n];
        #pragma unroll
        for (int reg = 0; reg < 4; reg++)
            f[reg][t] = fast_tanh(acc[t][reg] + kp_buf[(size_t)(tokD0 + reg) * DS + n] + fb);
    }

    #pragma unroll
    for (int t = 0; t < 4; t++) acc[t] = (f32x4){0.f,0.f,0.f,0.f};
    mfma_group(Rf, bfB, acc);
    #pragma unroll
    for (int t = 0; t < 4; t++) {
        const int n = (4 + t) * 16 + L15;
        const float fb = fB[n];
        #pragma unroll
        for (int reg = 0; reg < 4; reg++)
            f[reg][4 + t] = fast_tanh(acc[t][reg] + kp_buf[(size_t)(tokD0 + reg) * DS + n] + fb);
    }

    #pragma unroll
    for (int reg = 0; reg < 4; reg++) {
        const int tok = tokD0 + reg;
        const int t = tok % Tn;
        const bool act = (t < Tn - 1);
        int sn = 0, ix = 0;
        float contrib = 0.f;
        if (act) {
            sn = skill[tok + 1];
            ix = (sn < NUMC) ? sn : (NUMC - 1);
            const float* pr = pW + (size_t)ix * DS + L15;
            #pragma unroll
            for (int nt = 0; nt < 8; nt++)
                contrib = fmaf(f[reg][nt], pr[nt * 16], contrib);
        }
        #pragma unroll
        for (int msk = 1; msk <= 8; msk <<= 1)
            contrib += __shfl_xor(contrib, msk);
        if (act && L15 == 0) {
            const float val = contrib + pB[ix];
            const float prd = (sn < NUMC) ? fast_sigmoid(val) : 0.f;
            out[(size_t)(tok / Tn) * (Tn - 1) + t] = prd;
        }
    }
}

extern "C" void kernel_launch(void* const* d_in, const int* in_sizes, int n_in,
                              void* d_out, int out_size, void* d_ws, size_t ws_size,
                              hipStream_t stream)
{
    const int*   skill  = (const int*)  d_in[0];
    const int*   answer = (const int*)  d_in[1];
    const float* k_emb  = (const float*)d_in[2];
    const float* v_emb  = (const float*)d_in[3];
    const float* Mk     = (const float*)d_in[4];
    const float* Mv0    = (const float*)d_in[5];
    const float* f_W    = (const float*)d_in[6];
    const float* f_b    = (const float*)d_in[7];
    const float* p_W    = (const float*)d_in[8];
    const float* p_b    = (const float*)d_in[9];
    const float* e_W    = (const float*)d_in[10];
    const float* e_b    = (const float*)d_in[11];
    const float* a_W    = (const float*)d_in[12];
    const float* a_b    = (const float*)d_in[13];
    float* out = (float*)d_out;

    float* ws     = (float*)d_ws;
    float* w2     = ws;                                        // NTOK*80 f32
    unsigned int* ea32 = (unsigned int*)(w2 + (size_t)NTOK*80); // NTOK*DS u32
    float* kp_buf = (float*)(ea32 + (size_t)NTOK*DS);          // NTOK*DS f32
    unsigned short* part16 = (unsigned short*)(kp_buf + (size_t)NTOK*DS);  // WG2*NTOK*DS ushort
    unsigned int* BeaU = (unsigned int*)(part16 + (size_t)WG2*NTOK*DS);
    unsigned int* BkmU = BeaU + 4096 * 4;
    unsigned int* Bf0U = BkmU + 3072 * 4;
    // total ~50 MB of d_ws

    k0_cast<<<36, 256, 0, stream>>>(e_W, a_W, f_W, Mk, BeaU, BkmU, Bf0U);
    k1_gemm<<<2*(NTOK/16), 64, 0, stream>>>(skill, answer, k_emb, v_emb,
        BeaU, BkmU, e_b, a_b, w2, ea32, kp_buf);
    k2_scan<<<Bsz*2*WG2, 64, 0, stream>>>(w2, ea32, Mv0, part16);
    k3_gemm<<<NTOK/16, 64, 0, stream>>>(part16, kp_buf, Bf0U, f_b,
        p_W, p_b, skill, out);
}